// Round 1
// baseline (260.722 us; speedup 1.0000x reference)
//
#include <hip/hip_runtime.h>
#include <math.h>

#define T_STEPS 96
#define N_NODES 128
#define B_SZ 64
#define H_SZ 64

typedef __attribute__((ext_vector_type(8))) __bf16 bf16x8;
typedef __attribute__((ext_vector_type(4))) float f32x4;

__device__ __forceinline__ float sigm(float v){ return 1.0f/(1.0f+__expf(-v)); }
__device__ __forceinline__ float tanh_fast(float v){
  float e = __expf(2.0f*v);
  return 1.0f - 2.0f/(e+1.0f);
}

// ---------------- LSTM kernel ----------------
// grid = 512: block = (node n = blockIdx>>2, batch-quarter bq = blockIdx&3)
// block = 256 threads = 4 waves; wave wv owns h-range [16wv,16wv+16) for all 4 gates.
// gates[16b x 256] = h[16b x 64] @ w_n[1:65][256]  (3-term bf16 hi/lo split MFMA)
//                  + x*w_n[0] + bias               (exact fp32)
__global__ __launch_bounds__(256, 2) void lstm_kernel(
    const float* __restrict__ x, const float* __restrict__ w,
    const float* __restrict__ bias, float* __restrict__ yout)
{
  __shared__ __align__(16) unsigned short hHi[16*72]; // [16 batches][64 h + pad]
  __shared__ __align__(16) unsigned short hLo[16*72];

  const int n   = blockIdx.x >> 2;
  const int bq  = blockIdx.x & 3;
  const int tid = threadIdx.x;
  const int wv  = tid >> 6;
  const int ln  = tid & 63;
  const int l15 = ln & 15;
  const int q   = ln >> 4;          // lane quad
  const int hh  = wv*16 + l15;      // h index this lane owns (col within each gate)

  for (int i = tid; i < 16*72; i += 256){ hHi[i] = 0; hLo[i] = 0; }

  // persistent B-fragments (w) in VGPRs: B[k][col], k = ks*32 + q*8 + j
  const float* wn = w + n*(65*256);
  bf16x8 bHi[4][2], bLo[4][2];
  float w0g[4], bg[4];
#pragma unroll
  for (int g = 0; g < 4; ++g){
    const int col = g*64 + hh;
    w0g[g] = wn[col];               // row 0 = x weight
    bg[g]  = bias[n*256 + col];
#pragma unroll
    for (int ks = 0; ks < 2; ++ks){
#pragma unroll
      for (int j = 0; j < 8; ++j){
        float wf = wn[(1 + ks*32 + q*8 + j)*256 + col];
        __bf16 hi = (__bf16)wf;
        __bf16 lo = (__bf16)(wf - (float)hi);
        bHi[g][ks][j] = hi;
        bLo[g][ks][j] = lo;
      }
    }
  }

  float c[4]    = {0.f,0.f,0.f,0.f};
  float hsum[4] = {0.f,0.f,0.f,0.f};
  const int bbase = bq*16 + q*4;    // this lane's 4 batch rows (C/D rows)
  float xc[4];
#pragma unroll
  for (int r = 0; r < 4; ++r) xc[r] = x[(bbase+r)*(T_STEPS*N_NODES) + n];

  __syncthreads();

#pragma unroll 1
  for (int t = 0; t < T_STEPS; ++t){
    // A-fragments: A[m=l15][k=q*8+j (+32 for ks=1)]
    bf16x8 aHi0 = *(const bf16x8*)&hHi[l15*72 +  0 + q*8];
    bf16x8 aHi1 = *(const bf16x8*)&hHi[l15*72 + 32 + q*8];
    bf16x8 aLo0 = *(const bf16x8*)&hLo[l15*72 +  0 + q*8];
    bf16x8 aLo1 = *(const bf16x8*)&hLo[l15*72 + 32 + q*8];

    const int tn = (t+1 < T_STEPS) ? (t+1) : t;   // prefetch x for next step
    float xn[4];
#pragma unroll
    for (int r = 0; r < 4; ++r)
      xn[r] = x[(bbase+r)*(T_STEPS*N_NODES) + tn*N_NODES + n];

    f32x4 acc[4];
#pragma unroll
    for (int g = 0; g < 4; ++g){
      f32x4 a;
#pragma unroll
      for (int r = 0; r < 4; ++r) a[r] = fmaf(xc[r], w0g[g], bg[g]);
      a = __builtin_amdgcn_mfma_f32_16x16x32_bf16(aLo0, bHi[g][0], a, 0,0,0);
      a = __builtin_amdgcn_mfma_f32_16x16x32_bf16(aHi0, bLo[g][0], a, 0,0,0);
      a = __builtin_amdgcn_mfma_f32_16x16x32_bf16(aHi0, bHi[g][0], a, 0,0,0);
      a = __builtin_amdgcn_mfma_f32_16x16x32_bf16(aLo1, bHi[g][1], a, 0,0,0);
      a = __builtin_amdgcn_mfma_f32_16x16x32_bf16(aHi1, bLo[g][1], a, 0,0,0);
      a = __builtin_amdgcn_mfma_f32_16x16x32_bf16(aHi1, bHi[g][1], a, 0,0,0);
      acc[g] = a;
    }
    __syncthreads();   // all A-reads of old h complete before overwriting h

#pragma unroll
    for (int r = 0; r < 4; ++r){
      float ig = acc[0][r], fg = acc[1][r], og = acc[2][r], ct = acc[3][r];
      float cn = sigm(fg)*c[r] + sigm(ig)*ct;   // NOTE: no tanh on c_tilda
      c[r] = cn;
      float hn = sigm(og)*tanh_fast(cn);
      hsum[r] += hn;
      __bf16 hi = (__bf16)hn;
      __bf16 lo = (__bf16)(hn - (float)hi);
      hHi[(q*4+r)*72 + hh] = __builtin_bit_cast(unsigned short, hi);
      hLo[(q*4+r)*72 + hh] = __builtin_bit_cast(unsigned short, lo);
      xc[r] = xn[r];
    }
    __syncthreads();   // new h visible for next step
  }

#pragma unroll
  for (int r = 0; r < 4; ++r){
    const int b = bbase + r;
    yout[(b*N_NODES + n)*H_SZ + hh] = hsum[r];
  }
}

// ---------------- DFT kernel: m = rfft(y, axis=n, ortho) ----------------
// grid = 256: (b = blockIdx>>2, h-group of 16 = blockIdx&3)
__global__ __launch_bounds__(256, 2) void dft_kernel(
    const float* __restrict__ y, float* __restrict__ Mout)
{
  __shared__ __align__(16) float ysl[128*20];   // [n][16h + pad4]
  __shared__ float twc[128], tws[128];
  const int b   = blockIdx.x >> 2;
  const int hg  = blockIdx.x & 3;
  const int tid = threadIdx.x;

  if (tid < 128){
    float ang = (float)((double)tid * 0.04908738521234052); // 2*pi/128
    twc[tid] = cosf(ang);
    tws[tid] = sinf(ang);
  }
  for (int i = tid; i < 128*16; i += 256){
    int nn = i >> 4, h = i & 15;
    ysl[nn*20 + h] = y[(b*N_NODES + nn)*H_SZ + hg*16 + h];
  }
  __syncthreads();

  for (int o = tid; o < 65*4; o += 256){
    int k  = o >> 2;
    int hq = o & 3;
    float re0=0,re1=0,re2=0,re3=0,im0=0,im1=0,im2=0,im3=0;
    for (int nn = 0; nn < 128; ++nn){
      float4 yv = *(const float4*)&ysl[nn*20 + hq*4];
      int j = (k*nn) & 127;
      float cc = twc[j], ss = tws[j];
      re0 = fmaf(yv.x, cc, re0); im0 = fmaf(yv.x, -ss, im0);
      re1 = fmaf(yv.y, cc, re1); im1 = fmaf(yv.y, -ss, im1);
      re2 = fmaf(yv.z, cc, re2); im2 = fmaf(yv.z, -ss, im2);
      re3 = fmaf(yv.w, cc, re3); im3 = fmaf(yv.w, -ss, im3);
    }
    const float s = 0.08838834764831845f;  // 1/sqrt(128) (ortho)
    const int hb = hg*16 + hq*4;
    float* mre = Mout + ((b*2+0)*65 + k)*H_SZ + hb;
    float* mim = Mout + ((b*2+1)*65 + k)*H_SZ + hb;
    mre[0]=re0*s; mre[1]=re1*s; mre[2]=re2*s; mre[3]=re3*s;
    mim[0]=im0*s; mim[1]=im1*s; mim[2]=im2*s; mim[3]=im3*s;
  }
}

// ---------------- epilogue: attention algebra + irfft-collapse + LN head ----------------
// grid = 64 (one block per batch b)
__global__ __launch_bounds__(256, 1) void post_kernel(
    const float* __restrict__ y, const float* __restrict__ Mws,
    const float* __restrict__ ln_g, const float* __restrict__ ln_b,
    const float* __restrict__ fc_w, const float* __restrict__ fc_b,
    float* __restrict__ out)
{
  __shared__ float Mre[65*65];   // [k][h] pad-65 (conflict-free both ways)
  __shared__ float Mim[65*65];
  __shared__ float twc[128], tws[128];
  __shared__ float Sre[64], Sim[64];
  __shared__ float gr[65], gi[65];
  __shared__ float Gre[64], Gim[64];
  __shared__ float att[128];
  __shared__ float PQ[65*2], AA[65*2];
  __shared__ float outv[64];

  const int b   = blockIdx.x;
  const int tid = threadIdx.x;

  if (tid < 128){
    float ang = (float)((double)tid * 0.04908738521234052);
    twc[tid] = cosf(ang);
    tws[tid] = sinf(ang);
  }
  for (int i = tid; i < 65*64; i += 256){
    int k = i >> 6, h = i & 63;
    Mre[k*65+h] = Mws[((b*2+0)*65 + k)*H_SZ + h];
    Mim[k*65+h] = Mws[((b*2+1)*65 + k)*H_SZ + h];
  }
  __syncthreads();

  // S[h] = sum_k m[k,h]
  if (tid < 64){
    float sr=0, si=0;
    for (int k = 0; k < 65; ++k){ sr += Mre[k*65+tid]; si += Mim[k*65+tid]; }
    Sre[tid]=sr; Sim[tid]=si;
  }
  __syncthreads();

  // sq[k] = mean_{f2,h} m[k]*m[f2] = (1/4160) sum_h m[k,h]*S[h];  g = csigmoid(crelu(sq))
  if (tid < 65){
    float a=0, bb=0;
    for (int h = 0; h < 64; ++h){
      float mr = Mre[tid*65+h], mi = Mim[tid*65+h];
      a  += mr*Sre[h] - mi*Sim[h];
      bb += mr*Sim[h] + mi*Sre[h];
    }
    a  *= (1.0f/4160.0f);  bb *= (1.0f/4160.0f);
    a = fmaxf(a, 0.0f);    bb = fmaxf(bb, 0.0f);        // crelu
    float t  = __expf(-a);
    float cb = cosf(bb), sb = sinf(bb);
    float dre = 1.0f + t*cb;                            // denom = 1 + e^{-z}
    float dim = t*sb;                                   // (imag = -dim)
    float nrm = dre*dre + dim*dim;
    gr[tid] = dre/nrm;
    gi[tid] = dim/nrm;
  }
  __syncthreads();

  // G[h] = sum_k g[k]*m[k,h]
  if (tid < 64){
    float grh=0, gih=0;
    for (int k = 0; k < 65; ++k){
      float mr = Mre[k*65+tid], mi = Mim[k*65+tid];
      float gk = gr[k], hk = gi[k];
      grh += gk*mr - hk*mi;
      gih += gk*mi + hk*mr;
    }
    Gre[tid]=grh; Gim[tid]=gih;
  }
  __syncthreads();

  // P[k],Q[k]: coefficients of v[n] = sum_h ImG[h]*H[n,h]
  if (tid < 65){
    float p=0, qq=0;
    for (int h = 0; h < 64; ++h){
      float gimh = Gim[h];
      p  += gimh * Mim[tid*65+h];
      qq += gimh * Mre[tid*65+h];
    }
    const float s2 = 2.0f*0.08838834764831845f;
    PQ[tid*2]   = p*s2;
    PQ[tid*2+1] = qq*s2;
  }
  __syncthreads();

  // att2[n] = sigmoid(relu((u[n]-v[n])/64)),  u[n] = sum_h ReG[h]*y[n,h]
  if (tid < 128){
    float u=0;
    for (int h = 0; h < 64; ++h) u += Gre[h]*y[(b*N_NODES + tid)*H_SZ + h];
    float v=0;
    for (int k = 1; k < 64; ++k){
      int j = (k*tid) & 127;
      v += PQ[k*2]*twc[j] + PQ[k*2+1]*tws[j];
    }
    float mean = (u - v)*(1.0f/64.0f);
    att[tid] = sigm(fmaxf(mean, 0.0f));
  }
  __syncthreads();

  // Ac[k], As[k]: att-weighted twiddle sums
  if (tid < 65){
    float ac=0, as=0;
    for (int nn = 0; nn < 128; ++nn){
      int j = (tid*nn) & 127;
      float a2 = att[nn];
      ac = fmaf(a2, twc[j], ac);
      as = fmaf(a2, tws[j], as);
    }
    const float s2 = 2.0f*0.08838834764831845f;
    AA[tid*2]   = ac*s2;
    AA[tid*2+1] = as*s2;
  }
  __syncthreads();

  // out[h] = ReG*sum_n att*y  -  ImG*sum_k (Mim*Ac + Mre*As)
  if (tid < 64){
    float wyh=0;
    for (int nn = 0; nn < 128; ++nn) wyh += att[nn]*y[(b*N_NODES + nn)*H_SZ + tid];
    float wHh=0;
    for (int k = 1; k < 64; ++k)
      wHh += Mim[k*65+tid]*AA[k*2] + Mre[k*65+tid]*AA[k*2+1];
    outv[tid] = Gre[tid]*wyh - Gim[tid]*wHh;
  }
  __syncthreads();

  // LayerNorm(H) -> Linear(H,1) -> sigmoid   (threads 0..63 = wave 0)
  if (tid < 64){
    float o = outv[tid];
    float s = o;
    for (int off = 32; off; off >>= 1) s += __shfl_xor(s, off, 64);
    float mu = s*(1.0f/64.0f);
    float d  = o - mu;
    float vv = d*d;
    for (int off = 32; off; off >>= 1) vv += __shfl_xor(vv, off, 64);
    float var = vv*(1.0f/64.0f);
    float zo = (d / sqrtf(var + 1e-5f))*ln_g[tid] + ln_b[tid];
    float z  = zo * fc_w[tid];
    for (int off = 32; off; off >>= 1) z += __shfl_xor(z, off, 64);
    if (tid == 0) out[b] = 1.0f/(1.0f + __expf(-(z + fc_b[0])));
  }
}

extern "C" void kernel_launch(void* const* d_in, const int* in_sizes, int n_in,
                              void* d_out, int out_size, void* d_ws, size_t ws_size,
                              hipStream_t stream) {
  (void)in_sizes; (void)n_in; (void)out_size; (void)ws_size;
  const float* x    = (const float*)d_in[0];
  const float* w    = (const float*)d_in[1];
  const float* bia  = (const float*)d_in[2];
  const float* ln_g = (const float*)d_in[3];
  const float* ln_b = (const float*)d_in[4];
  const float* fc_w = (const float*)d_in[5];
  const float* fc_b = (const float*)d_in[6];
  float* out = (float*)d_out;

  float* y = (float*)d_ws;                 // [64][128][64] fp32  (2 MB)
  float* M = y + (size_t)B_SZ*N_NODES*H_SZ; // [64][2][65][64] fp32 (~2.1 MB)

  lstm_kernel<<<dim3(512), dim3(256), 0, stream>>>(x, w, bia, y);
  dft_kernel <<<dim3(256), dim3(256), 0, stream>>>(y, M);
  post_kernel<<<dim3(64),  dim3(256), 0, stream>>>(y, M, ln_g, ln_b, fc_w, fc_b, out);
}

// Round 2
// 193.602 us; speedup vs baseline: 1.3467x; 1.3467x over previous
//
#include <hip/hip_runtime.h>
#include <math.h>

#define T_STEPS 96
#define N_NODES 128
#define B_SZ 64
#define H_SZ 64

typedef __attribute__((ext_vector_type(8))) __bf16 bf16x8;
typedef __attribute__((ext_vector_type(4))) float f32x4;

__device__ __forceinline__ float rcp_fast(float x){ return __builtin_amdgcn_rcpf(x); }
__device__ __forceinline__ float sigm(float v){ return rcp_fast(1.0f + __expf(-v)); }
__device__ __forceinline__ float tanh_fast(float v){
  float e = __expf(2.0f*v);                       // v_mul + v_exp
  return fmaf(-2.0f, rcp_fast(e + 1.0f), 1.0f);   // (e-1)/(e+1)
}

// ---------------- LSTM kernel ----------------
// grid = 512: block = (node n = blockIdx>>2, batch-quarter bq = blockIdx&3)
// 4 waves; wave wv owns h-range [16wv,16wv+16) for all 4 gates (lane-local cell update).
// gates[16b x 256] = h_bf16[16b x 64] @ (w_hi + w_lo)[64][256]  (2-term split, 16 MFMA/step)
//                  + x*w_row0 + bias  (exact fp32)
// h double-buffered in LDS -> ONE barrier per step. x staged in LDS up front.
__global__ __launch_bounds__(256, 2) void lstm_kernel(
    const float* __restrict__ x, const float* __restrict__ w,
    const float* __restrict__ bias, float* __restrict__ yout)
{
  __shared__ __align__(16) unsigned short hb[2][16*72]; // [buf][16 batches][64 h + 8 pad]
  __shared__ __align__(16) float xsl[T_STEPS*20];       // [t][16 b_local + 4 pad]

  const int n   = blockIdx.x >> 2;
  const int bq  = blockIdx.x & 3;
  const int tid = threadIdx.x;
  const int wv  = tid >> 6;
  const int ln  = tid & 63;
  const int l15 = ln & 15;
  const int q   = ln >> 4;          // lane quad
  const int hh  = wv*16 + l15;      // h col this lane owns (within each gate)

  for (int i = tid; i < 2*16*72; i += 256) hb[0][i] = 0;
  // stage x: x[bq*16+bl, t, n] -> xsl[t*20 + bl]
  for (int i = tid; i < T_STEPS*16; i += 256){
    int t2 = i >> 4, bl = i & 15;
    xsl[t2*20 + bl] = x[(bq*16 + bl)*(T_STEPS*N_NODES) + t2*N_NODES + n];
  }

  // persistent w B-fragments in VGPRs: B[k=ks*32+q*8+j][col=l15 of tile(g,wv)]
  const float* wn = w + n*(65*256);
  bf16x8 bHi[4][2], bLo[4][2];
  float w0g[4], bg[4];
#pragma unroll
  for (int g = 0; g < 4; ++g){
    const int col = g*64 + hh;
    w0g[g] = wn[col];               // row 0 = x weight
    bg[g]  = bias[n*256 + col];
#pragma unroll
    for (int ks = 0; ks < 2; ++ks){
#pragma unroll
      for (int j = 0; j < 8; ++j){
        float wf = wn[(1 + ks*32 + q*8 + j)*256 + col];
        __bf16 hi = (__bf16)wf;
        __bf16 lo = (__bf16)(wf - (float)hi);
        bHi[g][ks][j] = hi;
        bLo[g][ks][j] = lo;
      }
    }
  }

  float c[4]    = {0.f,0.f,0.f,0.f};
  float hsum[4] = {0.f,0.f,0.f,0.f};
  __syncthreads();

#pragma unroll 2
  for (int t = 0; t < T_STEPS; ++t){
    const unsigned short* cur = hb[t & 1];
    unsigned short*       nxt = hb[(t & 1) ^ 1];

    // A-fragments: A[m=l15][k=q*8+j (+32)]
    bf16x8 a0 = *(const bf16x8*)&cur[l15*72 +  0 + q*8];
    bf16x8 a1 = *(const bf16x8*)&cur[l15*72 + 32 + q*8];
    // x for this lane's 4 batch rows (b_local = q*4+r), broadcast LDS read
    float4 xv = *(const float4*)&xsl[t*20 + q*4];

    f32x4 acc[4];
#pragma unroll
    for (int g = 0; g < 4; ++g){
      f32x4 a;
      a[0] = fmaf(xv.x, w0g[g], bg[g]);
      a[1] = fmaf(xv.y, w0g[g], bg[g]);
      a[2] = fmaf(xv.z, w0g[g], bg[g]);
      a[3] = fmaf(xv.w, w0g[g], bg[g]);
      a = __builtin_amdgcn_mfma_f32_16x16x32_bf16(a0, bHi[g][0], a, 0,0,0);
      a = __builtin_amdgcn_mfma_f32_16x16x32_bf16(a0, bLo[g][0], a, 0,0,0);
      a = __builtin_amdgcn_mfma_f32_16x16x32_bf16(a1, bHi[g][1], a, 0,0,0);
      a = __builtin_amdgcn_mfma_f32_16x16x32_bf16(a1, bLo[g][1], a, 0,0,0);
      acc[g] = a;
    }

#pragma unroll
    for (int r = 0; r < 4; ++r){
      float ig = acc[0][r], fg = acc[1][r], og = acc[2][r], ct = acc[3][r];
      float cn = sigm(fg)*c[r] + sigm(ig)*ct;   // NOTE: no tanh on c_tilda
      c[r] = cn;
      float hn = sigm(og)*tanh_fast(cn);
      hsum[r] += hn;
      __bf16 hv = (__bf16)hn;
      nxt[(q*4+r)*72 + hh] = __builtin_bit_cast(unsigned short, hv);
    }
    __syncthreads();   // new h visible; old buffer free to overwrite next step
  }

#pragma unroll
  for (int r = 0; r < 4; ++r){
    const int b = bq*16 + q*4 + r;
    yout[(b*N_NODES + n)*H_SZ + hh] = hsum[r];
  }
}

// ---------------- DFT kernel: m = rfft(y, axis=n, ortho) ----------------
// grid = 256: (b = blockIdx>>2, h-group of 16 = blockIdx&3)
__global__ __launch_bounds__(256, 2) void dft_kernel(
    const float* __restrict__ y, float* __restrict__ Mout)
{
  __shared__ __align__(16) float ysl[128*20];   // [n][16h + pad4]
  __shared__ float twc[128], tws[128];
  const int b   = blockIdx.x >> 2;
  const int hg  = blockIdx.x & 3;
  const int tid = threadIdx.x;

  if (tid < 128){
    float ang = (float)((double)tid * 0.04908738521234052); // 2*pi/128
    twc[tid] = cosf(ang);
    tws[tid] = sinf(ang);
  }
  for (int i = tid; i < 128*16; i += 256){
    int nn = i >> 4, h = i & 15;
    ysl[nn*20 + h] = y[(b*N_NODES + nn)*H_SZ + hg*16 + h];
  }
  __syncthreads();

  for (int o = tid; o < 65*4; o += 256){
    int k  = o >> 2;
    int hq = o & 3;
    float re0=0,re1=0,re2=0,re3=0,im0=0,im1=0,im2=0,im3=0;
    for (int nn = 0; nn < 128; ++nn){
      float4 yv = *(const float4*)&ysl[nn*20 + hq*4];
      int j = (k*nn) & 127;
      float cc = twc[j], ss = tws[j];
      re0 = fmaf(yv.x, cc, re0); im0 = fmaf(yv.x, -ss, im0);
      re1 = fmaf(yv.y, cc, re1); im1 = fmaf(yv.y, -ss, im1);
      re2 = fmaf(yv.z, cc, re2); im2 = fmaf(yv.z, -ss, im2);
      re3 = fmaf(yv.w, cc, re3); im3 = fmaf(yv.w, -ss, im3);
    }
    const float s = 0.08838834764831845f;  // 1/sqrt(128) (ortho)
    const int hb2 = hg*16 + hq*4;
    float* mre = Mout + ((b*2+0)*65 + k)*H_SZ + hb2;
    float* mim = Mout + ((b*2+1)*65 + k)*H_SZ + hb2;
    mre[0]=re0*s; mre[1]=re1*s; mre[2]=re2*s; mre[3]=re3*s;
    mim[0]=im0*s; mim[1]=im1*s; mim[2]=im2*s; mim[3]=im3*s;
  }
}

// ---------------- epilogue: attention algebra + irfft-collapse + LN head ----------------
// grid = 64 (one block per batch b)
__global__ __launch_bounds__(256, 1) void post_kernel(
    const float* __restrict__ y, const float* __restrict__ Mws,
    const float* __restrict__ ln_g, const float* __restrict__ ln_b,
    const float* __restrict__ fc_w, const float* __restrict__ fc_b,
    float* __restrict__ out)
{
  __shared__ float Mre[65*65];   // [k][h] pad-65 (conflict-free both ways)
  __shared__ float Mim[65*65];
  __shared__ float twc[128], tws[128];
  __shared__ float Sre[64], Sim[64];
  __shared__ float gr[65], gi[65];
  __shared__ float Gre[64], Gim[64];
  __shared__ float att[128];
  __shared__ float PQ[65*2], AA[65*2];
  __shared__ float outv[64];

  const int b   = blockIdx.x;
  const int tid = threadIdx.x;

  if (tid < 128){
    float ang = (float)((double)tid * 0.04908738521234052);
    twc[tid] = cosf(ang);
    tws[tid] = sinf(ang);
  }
  for (int i = tid; i < 65*64; i += 256){
    int k = i >> 6, h = i & 63;
    Mre[k*65+h] = Mws[((b*2+0)*65 + k)*H_SZ + h];
    Mim[k*65+h] = Mws[((b*2+1)*65 + k)*H_SZ + h];
  }
  __syncthreads();

  // S[h] = sum_k m[k,h]
  if (tid < 64){
    float sr=0, si=0;
    for (int k = 0; k < 65; ++k){ sr += Mre[k*65+tid]; si += Mim[k*65+tid]; }
    Sre[tid]=sr; Sim[tid]=si;
  }
  __syncthreads();

  // sq[k] = (1/4160) sum_h m[k,h]*S[h];  g = csigmoid(crelu(sq))
  if (tid < 65){
    float a=0, bb=0;
    for (int h = 0; h < 64; ++h){
      float mr = Mre[tid*65+h], mi = Mim[tid*65+h];
      a  += mr*Sre[h] - mi*Sim[h];
      bb += mr*Sim[h] + mi*Sre[h];
    }
    a  *= (1.0f/4160.0f);  bb *= (1.0f/4160.0f);
    a = fmaxf(a, 0.0f);    bb = fmaxf(bb, 0.0f);        // crelu
    float t  = __expf(-a);
    float cb = cosf(bb), sb = sinf(bb);
    float dre = 1.0f + t*cb;                            // denom = 1 + e^{-z}
    float dim = t*sb;                                   // (imag = -dim)
    float nrm = rcp_fast(dre*dre + dim*dim);
    gr[tid] = dre*nrm;
    gi[tid] = dim*nrm;
  }
  __syncthreads();

  // G[h] = sum_k g[k]*m[k,h]
  if (tid < 64){
    float grh=0, gih=0;
    for (int k = 0; k < 65; ++k){
      float mr = Mre[k*65+tid], mi = Mim[k*65+tid];
      float gk = gr[k], hk = gi[k];
      grh += gk*mr - hk*mi;
      gih += gk*mi + hk*mr;
    }
    Gre[tid]=grh; Gim[tid]=gih;
  }
  __syncthreads();

  // P[k],Q[k]: coefficients of v[n] = sum_h ImG[h]*H[n,h]
  if (tid < 65){
    float p=0, qq=0;
    for (int h = 0; h < 64; ++h){
      float gimh = Gim[h];
      p  += gimh * Mim[tid*65+h];
      qq += gimh * Mre[tid*65+h];
    }
    const float s2 = 2.0f*0.08838834764831845f;
    PQ[tid*2]   = p*s2;
    PQ[tid*2+1] = qq*s2;
  }
  __syncthreads();

  // att2[n] = sigmoid(relu((u[n]-v[n])/64)),  u[n] = sum_h ReG[h]*y[n,h]
  if (tid < 128){
    float u=0;
    for (int h = 0; h < 64; ++h) u += Gre[h]*y[(b*N_NODES + tid)*H_SZ + h];
    float v=0;
    for (int k = 1; k < 64; ++k){
      int j = (k*tid) & 127;
      v += PQ[k*2]*twc[j] + PQ[k*2+1]*tws[j];
    }
    float mean = (u - v)*(1.0f/64.0f);
    att[tid] = sigm(fmaxf(mean, 0.0f));
  }
  __syncthreads();

  // Ac[k], As[k]: att-weighted twiddle sums
  if (tid < 65){
    float ac=0, as=0;
    for (int nn = 0; nn < 128; ++nn){
      int j = (tid*nn) & 127;
      float a2 = att[nn];
      ac = fmaf(a2, twc[j], ac);
      as = fmaf(a2, tws[j], as);
    }
    const float s2 = 2.0f*0.08838834764831845f;
    AA[tid*2]   = ac*s2;
    AA[tid*2+1] = as*s2;
  }
  __syncthreads();

  // out[h] = ReG*sum_n att*y  -  ImG*sum_k (Mim*Ac + Mre*As)
  if (tid < 64){
    float wyh=0;
    for (int nn = 0; nn < 128; ++nn) wyh += att[nn]*y[(b*N_NODES + nn)*H_SZ + tid];
    float wHh=0;
    for (int k = 1; k < 64; ++k)
      wHh += Mim[k*65+tid]*AA[k*2] + Mre[k*65+tid]*AA[k*2+1];
    outv[tid] = Gre[tid]*wyh - Gim[tid]*wHh;
  }
  __syncthreads();

  // LayerNorm(H) -> Linear(H,1) -> sigmoid   (threads 0..63 = wave 0)
  if (tid < 64){
    float o = outv[tid];
    float s = o;
    for (int off = 32; off; off >>= 1) s += __shfl_xor(s, off, 64);
    float mu = s*(1.0f/64.0f);
    float d  = o - mu;
    float vv = d*d;
    for (int off = 32; off; off >>= 1) vv += __shfl_xor(vv, off, 64);
    float var = vv*(1.0f/64.0f);
    float zo = (d / sqrtf(var + 1e-5f))*ln_g[tid] + ln_b[tid];
    float z  = zo * fc_w[tid];
    for (int off = 32; off; off >>= 1) z += __shfl_xor(z, off, 64);
    if (tid == 0) out[b] = 1.0f/(1.0f + __expf(-(z + fc_b[0])));
  }
}

extern "C" void kernel_launch(void* const* d_in, const int* in_sizes, int n_in,
                              void* d_out, int out_size, void* d_ws, size_t ws_size,
                              hipStream_t stream) {
  (void)in_sizes; (void)n_in; (void)out_size; (void)ws_size;
  const float* x    = (const float*)d_in[0];
  const float* w    = (const float*)d_in[1];
  const float* bia  = (const float*)d_in[2];
  const float* ln_g = (const float*)d_in[3];
  const float* ln_b = (const float*)d_in[4];
  const float* fc_w = (const float*)d_in[5];
  const float* fc_b = (const float*)d_in[6];
  float* out = (float*)d_out;

  float* y = (float*)d_ws;                  // [64][128][64] fp32  (2 MB)
  float* M = y + (size_t)B_SZ*N_NODES*H_SZ; // [64][2][65][64] fp32 (~2.1 MB)

  lstm_kernel<<<dim3(512), dim3(256), 0, stream>>>(x, w, bia, y);
  dft_kernel <<<dim3(256), dim3(256), 0, stream>>>(y, M);
  post_kernel<<<dim3(64),  dim3(256), 0, stream>>>(y, M, ln_g, ln_b, fc_w, fc_b, out);
}

// Round 4
// 181.544 us; speedup vs baseline: 1.4361x; 1.0664x over previous
//
#include <hip/hip_runtime.h>
#include <math.h>

#define T_STEPS 96
#define N_NODES 128
#define B_SZ 64
#define H_SZ 64

typedef __attribute__((ext_vector_type(8))) __bf16 bf16x8;
typedef __attribute__((ext_vector_type(4))) float f32x4;

__device__ __forceinline__ float rcp_fast(float x){ return __builtin_amdgcn_rcpf(x); }
__device__ __forceinline__ float sigm(float v){ return rcp_fast(1.0f + __expf(-v)); }
__device__ __forceinline__ float tanh_fast(float v){
  float e = __expf(2.0f*v);
  return fmaf(-2.0f, rcp_fast(e + 1.0f), 1.0f);
}

// ---------------- LSTM kernel ----------------
// grid = 512: (node n = blockIdx>>2, batch-quarter bq = blockIdx&3)
// 4 waves; wave wv owns h-cols [16wv,16wv+16) for all 4 gates (lane-local cell update).
// gates[16b x 256] = h_bf16[16b x 64] @ (w_hi + w_lo)  (2-term split, 16 MFMA/step)
// h double-buffered in LDS -> ONE barrier/step. x staged in LDS. Cell math packed f32x4.
__global__ __launch_bounds__(256, 2) void lstm_kernel(
    const float* __restrict__ x, const float* __restrict__ w,
    const float* __restrict__ bias, float* __restrict__ yout)
{
  __shared__ __align__(16) unsigned short hb[2][16*72]; // [buf][16 b][64 h + 8 pad]
  __shared__ __align__(16) float xsl[T_STEPS*20];       // [t][16 b_local + 4 pad]

  const int n   = blockIdx.x >> 2;
  const int bq  = blockIdx.x & 3;
  const int tid = threadIdx.x;
  const int wv  = tid >> 6;
  const int ln  = tid & 63;
  const int l15 = ln & 15;
  const int q   = ln >> 4;
  const int hh  = wv*16 + l15;

  for (int i = tid; i < 2*16*72; i += 256) hb[0][i] = 0;
  for (int i = tid; i < T_STEPS*16; i += 256){
    int t2 = i >> 4, bl = i & 15;
    xsl[t2*20 + bl] = x[(bq*16 + bl)*(T_STEPS*N_NODES) + t2*N_NODES + n];
  }

  const float* wn = w + n*(65*256);
  bf16x8 bHi[4][2], bLo[4][2];
  float w0g[4], bg[4];
#pragma unroll
  for (int g = 0; g < 4; ++g){
    const int col = g*64 + hh;
    w0g[g] = wn[col];
    bg[g]  = bias[n*256 + col];
#pragma unroll
    for (int ks = 0; ks < 2; ++ks){
#pragma unroll
      for (int j = 0; j < 8; ++j){
        float wf = wn[(1 + ks*32 + q*8 + j)*256 + col];
        __bf16 hi = (__bf16)wf;
        __bf16 lo = (__bf16)(wf - (float)hi);
        bHi[g][ks][j] = hi;
        bLo[g][ks][j] = lo;
      }
    }
  }

  f32x4 cv  = {0.f,0.f,0.f,0.f};
  f32x4 hsv = {0.f,0.f,0.f,0.f};
  __syncthreads();

#pragma unroll 2
  for (int t = 0; t < T_STEPS; ++t){
    const unsigned short* cur = hb[t & 1];
    unsigned short*       nxt = hb[(t & 1) ^ 1];

    bf16x8 a0 = *(const bf16x8*)&cur[l15*72 +  0 + q*8];
    bf16x8 a1 = *(const bf16x8*)&cur[l15*72 + 32 + q*8];
    f32x4 xv = *(const f32x4*)&xsl[t*20 + q*4];   // 16B-aligned (20 and q*4 are %4)

    f32x4 acc[4];
#pragma unroll
    for (int g = 0; g < 4; ++g){
      f32x4 a = xv * w0g[g] + bg[g];              // packed init
      a = __builtin_amdgcn_mfma_f32_16x16x32_bf16(a0, bHi[g][0], a, 0,0,0);
      a = __builtin_amdgcn_mfma_f32_16x16x32_bf16(a0, bLo[g][0], a, 0,0,0);
      a = __builtin_amdgcn_mfma_f32_16x16x32_bf16(a1, bHi[g][1], a, 0,0,0);
      a = __builtin_amdgcn_mfma_f32_16x16x32_bf16(a1, bLo[g][1], a, 0,0,0);
      acc[g] = a;
    }

    f32x4 sI, sF, sO;
#pragma unroll
    for (int r = 0; r < 4; ++r){
      sI[r] = sigm(acc[0][r]);
      sF[r] = sigm(acc[1][r]);
      sO[r] = sigm(acc[2][r]);
    }
    cv = sF*cv + sI*acc[3];                       // packed cell update (no tanh on c_tilda)
    f32x4 th;
#pragma unroll
    for (int r = 0; r < 4; ++r) th[r] = tanh_fast(cv[r]);
    f32x4 hn = sO*th;
    hsv += hn;
#pragma unroll
    for (int r = 0; r < 4; ++r){
      __bf16 hv = (__bf16)hn[r];
      nxt[(q*4+r)*72 + hh] = __builtin_bit_cast(unsigned short, hv);
    }
    __syncthreads();
  }

#pragma unroll
  for (int r = 0; r < 4; ++r){
    const int b = bq*16 + q*4 + r;
    yout[(b*N_NODES + n)*H_SZ + hh] = hsv[r];
  }
}

// ---------------- DFT kernel: m = rfft(y, axis=n, ortho) ----------------
// grid = 256: (b = blockIdx>>2, h-group of 16 = blockIdx&3)
__global__ __launch_bounds__(256, 2) void dft_kernel(
    const float* __restrict__ y, float* __restrict__ Mout)
{
  __shared__ __align__(16) float ysl[128*20];
  __shared__ float twc[128], tws[128];
  const int b   = blockIdx.x >> 2;
  const int hg  = blockIdx.x & 3;
  const int tid = threadIdx.x;

  if (tid < 128){
    float ang = (float)((double)tid * 0.04908738521234052); // 2*pi/128
    twc[tid] = cosf(ang);
    tws[tid] = sinf(ang);
  }
  for (int i = tid; i < 128*16; i += 256){
    int nn = i >> 4, h = i & 15;
    ysl[nn*20 + h] = y[(b*N_NODES + nn)*H_SZ + hg*16 + h];
  }
  __syncthreads();

  for (int o = tid; o < 65*4; o += 256){
    int k  = o >> 2;
    int hq = o & 3;
    float re0=0,re1=0,re2=0,re3=0,im0=0,im1=0,im2=0,im3=0;
    for (int nn = 0; nn < 128; ++nn){
      float4 yv = *(const float4*)&ysl[nn*20 + hq*4];
      int j = (k*nn) & 127;
      float cc = twc[j], ss = tws[j];
      re0 = fmaf(yv.x, cc, re0); im0 = fmaf(yv.x, -ss, im0);
      re1 = fmaf(yv.y, cc, re1); im1 = fmaf(yv.y, -ss, im1);
      re2 = fmaf(yv.z, cc, re2); im2 = fmaf(yv.z, -ss, im2);
      re3 = fmaf(yv.w, cc, re3); im3 = fmaf(yv.w, -ss, im3);
    }
    const float s = 0.08838834764831845f;  // 1/sqrt(128)
    const int hb2 = hg*16 + hq*4;
    float* mre = Mout + ((b*2+0)*65 + k)*H_SZ + hb2;
    float* mim = Mout + ((b*2+1)*65 + k)*H_SZ + hb2;
    mre[0]=re0*s; mre[1]=re1*s; mre[2]=re2*s; mre[3]=re3*s;
    mim[0]=im0*s; mim[1]=im1*s; mim[2]=im2*s; mim[3]=im3*s;
  }
}

// ---------------- epilogue: all-LDS attention algebra + irfft-collapse + LN head ----
// grid = 64 (one block per batch b). Everything staged to LDS up front.
__global__ __launch_bounds__(256, 1) void post_kernel(
    const float* __restrict__ y, const float* __restrict__ Mws,
    const float* __restrict__ ln_g, const float* __restrict__ ln_b,
    const float* __restrict__ fc_w, const float* __restrict__ fc_b,
    float* __restrict__ out)
{
  __shared__ float ysh[128*65];  // [n][h] stride 65: conflict-free row & col access
  __shared__ float Mre[65*65];   // [k][h] stride 65
  __shared__ float Mim[65*65];
  __shared__ float twc[128], tws[128];
  __shared__ float Sre[64], Sim[64];
  __shared__ float gr[65], gi[65];
  __shared__ float Gre[64], Gim[64];
  __shared__ float att[128];
  __shared__ float PQ[65*2], AA[65*2];
  __shared__ float outv[64];

  const int b   = blockIdx.x;
  const int tid = threadIdx.x;

  if (tid < 128){
    float ang = (float)((double)tid * 0.04908738521234052);
    twc[tid] = cosf(ang);
    tws[tid] = sinf(ang);
  }
  // stage y[b]: 128x64 floats, coalesced float4
  for (int i = tid; i < 128*16; i += 256){
    int nn = i >> 4, h4 = (i & 15)*4;
    float4 v = *(const float4*)&y[(b*N_NODES + nn)*H_SZ + h4];
    ysh[nn*65 + h4+0] = v.x; ysh[nn*65 + h4+1] = v.y;
    ysh[nn*65 + h4+2] = v.z; ysh[nn*65 + h4+3] = v.w;
  }
  // stage M
  for (int i = tid; i < 65*16; i += 256){
    int k = i >> 4, h4 = (i & 15)*4;
    float4 vr = *(const float4*)&Mws[((b*2+0)*65 + k)*H_SZ + h4];
    float4 vi = *(const float4*)&Mws[((b*2+1)*65 + k)*H_SZ + h4];
    Mre[k*65 + h4+0] = vr.x; Mre[k*65 + h4+1] = vr.y;
    Mre[k*65 + h4+2] = vr.z; Mre[k*65 + h4+3] = vr.w;
    Mim[k*65 + h4+0] = vi.x; Mim[k*65 + h4+1] = vi.y;
    Mim[k*65 + h4+2] = vi.z; Mim[k*65 + h4+3] = vi.w;
  }
  __syncthreads();

  // S[h] = sum_k m[k,h]
  if (tid < 64){
    float sr=0, si=0;
    for (int k = 0; k < 65; ++k){ sr += Mre[k*65+tid]; si += Mim[k*65+tid]; }
    Sre[tid]=sr; Sim[tid]=si;
  }
  __syncthreads();

  // sq[k] = (1/4160) sum_h m[k,h]*S[h];  g = csigmoid(crelu(sq))
  if (tid < 65){
    float a=0, bb=0;
    for (int h = 0; h < 64; ++h){
      float mr = Mre[tid*65+h], mi = Mim[tid*65+h];
      a  += mr*Sre[h] - mi*Sim[h];
      bb += mr*Sim[h] + mi*Sre[h];
    }
    a  *= (1.0f/4160.0f);  bb *= (1.0f/4160.0f);
    a = fmaxf(a, 0.0f);    bb = fmaxf(bb, 0.0f);
    float t  = __expf(-a);
    float cb = cosf(bb), sb = sinf(bb);
    float dre = 1.0f + t*cb;
    float dim = t*sb;
    float nrm = rcp_fast(dre*dre + dim*dim);
    gr[tid] = dre*nrm;
    gi[tid] = dim*nrm;
  }
  __syncthreads();

  // G[h] = sum_k g[k]*m[k,h]
  if (tid < 64){
    float grh=0, gih=0;
    for (int k = 0; k < 65; ++k){
      float mr = Mre[k*65+tid], mi = Mim[k*65+tid];
      float gk = gr[k], hk = gi[k];
      grh += gk*mr - hk*mi;
      gih += gk*mi + hk*mr;
    }
    Gre[tid]=grh; Gim[tid]=gih;
  }
  __syncthreads();

  // P[k],Q[k]: coefficients of v[n] = sum_h ImG[h]*H[n,h]
  if (tid < 65){
    float p=0, qq=0;
    for (int h = 0; h < 64; ++h){
      float gimh = Gim[h];
      p  += gimh * Mim[tid*65+h];
      qq += gimh * Mre[tid*65+h];
    }
    const float s2 = 2.0f*0.08838834764831845f;
    PQ[tid*2]   = p*s2;
    PQ[tid*2+1] = qq*s2;
  }
  __syncthreads();

  // att2[n] = sigmoid(relu((u[n]-v[n])/64)),  u[n] = sum_h ReG[h]*y[n,h]
  if (tid < 128){
    float u=0;
    for (int h = 0; h < 64; ++h) u += Gre[h]*ysh[tid*65+h];
    float v=0;
    for (int k = 1; k < 64; ++k){
      int j = (k*tid) & 127;
      v += PQ[k*2]*twc[j] + PQ[k*2+1]*tws[j];
    }
    float mean = (u - v)*(1.0f/64.0f);
    att[tid] = sigm(fmaxf(mean, 0.0f));
  }
  __syncthreads();

  // Ac[k], As[k]
  if (tid < 65){
    float ac=0, as=0;
    for (int nn = 0; nn < 128; ++nn){
      int j = (tid*nn) & 127;
      float a2 = att[nn];
      ac = fmaf(a2, twc[j], ac);
      as = fmaf(a2, tws[j], as);
    }
    const float s2 = 2.0f*0.08838834764831845f;
    AA[tid*2]   = ac*s2;
    AA[tid*2+1] = as*s2;
  }
  __syncthreads();

  // out[h] = ReG*sum_n att*y  -  ImG*sum_k (Mim*Ac + Mre*As)
  if (tid < 64){
    float wyh=0;
    for (int nn = 0; nn < 128; ++nn) wyh += att[nn]*ysh[nn*65+tid];
    float wHh=0;
    for (int k = 1; k < 64; ++k)
      wHh += Mim[k*65+tid]*AA[k*2] + Mre[k*65+tid]*AA[k*2+1];
    outv[tid] = Gre[tid]*wyh - Gim[tid]*wHh;
  }
  __syncthreads();

  // LayerNorm(H) -> Linear(H,1) -> sigmoid
  if (tid < 64){
    float o = outv[tid];
    float s = o;
    for (int off = 32; off; off >>= 1) s += __shfl_xor(s, off, 64);
    float mu = s*(1.0f/64.0f);
    float d  = o - mu;
    float vv = d*d;
    for (int off = 32; off; off >>= 1) vv += __shfl_xor(vv, off, 64);
    float var = vv*(1.0f/64.0f);
    float zo = (d / sqrtf(var + 1e-5f))*ln_g[tid] + ln_b[tid];
    float z  = zo * fc_w[tid];
    for (int off = 32; off; off >>= 1) z += __shfl_xor(z, off, 64);
    if (tid == 0) out[b] = 1.0f/(1.0f + __expf(-(z + fc_b[0])));
  }
}

extern "C" void kernel_launch(void* const* d_in, const int* in_sizes, int n_in,
                              void* d_out, int out_size, void* d_ws, size_t ws_size,
                              hipStream_t stream) {
  (void)in_sizes; (void)n_in; (void)out_size; (void)ws_size;
  const float* x    = (const float*)d_in[0];
  const float* w    = (const float*)d_in[1];
  const float* bia  = (const float*)d_in[2];
  const float* ln_g = (const float*)d_in[3];
  const float* ln_b = (const float*)d_in[4];
  const float* fc_w = (const float*)d_in[5];
  const float* fc_b = (const float*)d_in[6];
  float* out = (float*)d_out;

  float* y = (float*)d_ws;                  // [64][128][64] fp32  (2 MB)
  float* M = y + (size_t)B_SZ*N_NODES*H_SZ; // [64][2][65][64] fp32 (~2.1 MB)

  lstm_kernel<<<dim3(512), dim3(256), 0, stream>>>(x, w, bia, y);
  dft_kernel <<<dim3(256), dim3(256), 0, stream>>>(y, M);
  post_kernel<<<dim3(64),  dim3(256), 0, stream>>>(y, M, ln_g, ln_b, fc_w, fc_b, out);
}

// Round 5
// 165.621 us; speedup vs baseline: 1.5742x; 1.0961x over previous
//
#include <hip/hip_runtime.h>
#include <math.h>

#define T_STEPS 96
#define N_NODES 128
#define B_SZ 64
#define H_SZ 64

typedef __attribute__((ext_vector_type(8))) __bf16 bf16x8;
typedef __attribute__((ext_vector_type(4))) float f32x4;

__device__ __forceinline__ float rcp_fast(float x){ return __builtin_amdgcn_rcpf(x); }
__device__ __forceinline__ float exp2_fast(float x){ return __builtin_amdgcn_exp2f(x); }
__device__ __forceinline__ float sigm(float v){ return rcp_fast(1.0f + __expf(-v)); }

// ---------------- LSTM kernel (transposed MFMA) ----------------
// grid = 512: (node n = blockIdx>>2, batch-quarter bq = blockIdx&3)
// D = A*B: A = W^T chunk (persistent VGPR, bf16, i/f/o pre-scaled by log2e),
//          B = h (bf16, LDS double-buffered), D[m=gate-col][n=batch].
// Lane owns batch l15 and 4 CONSECUTIVE h (wv*16+q*4+r) for all 4 gates ->
// lane-local cell update, packed bf16 h-write (1 ds_write_b64), float4 y-store.
// 8 MFMA/step (bf16 weights, no lo-split). 1 barrier/step.
__global__ __launch_bounds__(256, 2) void lstm_kernel(
    const float* __restrict__ x, const float* __restrict__ w,
    const float* __restrict__ bias, float* __restrict__ yout)
{
  __shared__ __align__(16) unsigned short hb[2][16*72]; // [buf][batch][64 h + 8 pad]
  __shared__ float xsl[T_STEPS*16];                     // [t][16 local batches]

  const int n   = blockIdx.x >> 2;
  const int bq  = blockIdx.x & 3;
  const int tid = threadIdx.x;
  const int wv  = tid >> 6;
  const int ln  = tid & 63;
  const int l15 = ln & 15;
  const int q   = ln >> 4;

  for (int i = tid; i < 2*16*72; i += 256) ((unsigned short*)hb)[i] = 0;
  for (int i = tid; i < T_STEPS*16; i += 256){
    int t2 = i >> 4, bl = i & 15;
    xsl[i] = x[(bq*16 + bl)*(T_STEPS*N_NODES) + t2*N_NODES + n];
  }

  const float LOG2E = 1.4426950408889634f;
  const float* wn = w + n*(65*256);

  // A-fragment (per lane): A[m=l15][k=q*8+j (+32)] = w[1+k][g*64+wv*16+l15]*scale
  bf16x8 aF[4][2];
  f32x4 w04[4], bg4[4];
#pragma unroll
  for (int g = 0; g < 4; ++g){
    const float sc = (g < 3) ? LOG2E : 1.0f;   // i,f,o in log2 domain; c_tilda true
    const int colA = g*64 + wv*16 + l15;
#pragma unroll
    for (int ks = 0; ks < 2; ++ks)
#pragma unroll
      for (int j = 0; j < 8; ++j)
        aF[g][ks][j] = (__bf16)(wn[(1 + ks*32 + q*8 + j)*256 + colA] * sc);
    // D-side per-lane rows m = q*4+r
#pragma unroll
    for (int r = 0; r < 4; ++r){
      const int colD = g*64 + wv*16 + q*4 + r;
      w04[g][r] = wn[colD] * sc;
      bg4[g][r] = bias[n*256 + colD] * sc;
    }
  }

  f32x4 cv  = {0.f,0.f,0.f,0.f};
  f32x4 hsv = {0.f,0.f,0.f,0.f};
  __syncthreads();

#pragma unroll 2
  for (int t = 0; t < T_STEPS; ++t){
    const unsigned short* cur = hb[t & 1];
    unsigned short*       nxt = (unsigned short*)hb[(t & 1) ^ 1];

    // B-fragment: B[k=q*8+j][n=l15] = h[batch l15][h=k]
    bf16x8 b0 = *(const bf16x8*)&cur[l15*72 +  0 + q*8];
    bf16x8 b1 = *(const bf16x8*)&cur[l15*72 + 32 + q*8];
    float xv = xsl[t*16 + l15];                 // broadcast within quad-groups

    f32x4 acc[4];
#pragma unroll
    for (int g = 0; g < 4; ++g){
      f32x4 a = w04[g]*xv + bg4[g];             // rows' x/bias init (fp32 exact)
      a = __builtin_amdgcn_mfma_f32_16x16x32_bf16(aF[g][0], b0, a, 0,0,0);
      a = __builtin_amdgcn_mfma_f32_16x16x32_bf16(aF[g][1], b1, a, 0,0,0);
      acc[g] = a;
    }

    f32x4 sI, sF, sO, th;
#pragma unroll
    for (int r = 0; r < 4; ++r){
      sI[r] = rcp_fast(1.0f + exp2_fast(-acc[0][r]));   // sigmoid, log2 domain
      sF[r] = rcp_fast(1.0f + exp2_fast(-acc[1][r]));
      sO[r] = rcp_fast(1.0f + exp2_fast(-acc[2][r]));
    }
    cv = sF*cv + sI*acc[3];                     // no tanh on c_tilda
#pragma unroll
    for (int r = 0; r < 4; ++r){
      float e = exp2_fast(cv[r]*2.8853900817779268f);   // exp(2c)
      th[r] = fmaf(-2.0f, rcp_fast(e + 1.0f), 1.0f);    // tanh, inf-safe
    }
    f32x4 hn = sO*th;
    hsv += hn;

    ushort4 pk;
    pk.x = __builtin_bit_cast(unsigned short, (__bf16)hn[0]);
    pk.y = __builtin_bit_cast(unsigned short, (__bf16)hn[1]);
    pk.z = __builtin_bit_cast(unsigned short, (__bf16)hn[2]);
    pk.w = __builtin_bit_cast(unsigned short, (__bf16)hn[3]);
    *(ushort4*)&nxt[l15*72 + wv*16 + q*4] = pk;  // 8B store, 4 consecutive h
    __syncthreads();
  }

  float4 o4 = {hsv[0], hsv[1], hsv[2], hsv[3]};
  *(float4*)&yout[((bq*16 + l15)*N_NODES + n)*H_SZ + wv*16 + q*4] = o4;
}

// ---------------- DFT kernel: m = rfft(y, axis=n, ortho) ----------------
// grid = 256: (b = blockIdx>>2, h-group of 16 = blockIdx&3)
__global__ __launch_bounds__(256, 2) void dft_kernel(
    const float* __restrict__ y, float* __restrict__ Mout)
{
  __shared__ __align__(16) float ysl[128*20];
  __shared__ float twc[128], tws[128];
  const int b   = blockIdx.x >> 2;
  const int hg  = blockIdx.x & 3;
  const int tid = threadIdx.x;

  if (tid < 128){
    float ang = (float)((double)tid * 0.04908738521234052); // 2*pi/128
    twc[tid] = cosf(ang);
    tws[tid] = sinf(ang);
  }
  for (int i = tid; i < 128*16; i += 256){
    int nn = i >> 4, h = i & 15;
    ysl[nn*20 + h] = y[(b*N_NODES + nn)*H_SZ + hg*16 + h];
  }
  __syncthreads();

  for (int o = tid; o < 65*4; o += 256){
    int k  = o >> 2;
    int hq = o & 3;
    float re0=0,re1=0,re2=0,re3=0,im0=0,im1=0,im2=0,im3=0;
    for (int nn = 0; nn < 128; ++nn){
      float4 yv = *(const float4*)&ysl[nn*20 + hq*4];
      int j = (k*nn) & 127;
      float cc = twc[j], ss = tws[j];
      re0 = fmaf(yv.x, cc, re0); im0 = fmaf(yv.x, -ss, im0);
      re1 = fmaf(yv.y, cc, re1); im1 = fmaf(yv.y, -ss, im1);
      re2 = fmaf(yv.z, cc, re2); im2 = fmaf(yv.z, -ss, im2);
      re3 = fmaf(yv.w, cc, re3); im3 = fmaf(yv.w, -ss, im3);
    }
    const float s = 0.08838834764831845f;  // 1/sqrt(128)
    const int hb2 = hg*16 + hq*4;
    float* mre = Mout + ((b*2+0)*65 + k)*H_SZ + hb2;
    float* mim = Mout + ((b*2+1)*65 + k)*H_SZ + hb2;
    mre[0]=re0*s; mre[1]=re1*s; mre[2]=re2*s; mre[3]=re3*s;
    mim[0]=im0*s; mim[1]=im1*s; mim[2]=im2*s; mim[3]=im3*s;
  }
}

// ---------------- epilogue: all-LDS attention algebra + irfft-collapse + LN head ----
// grid = 64 (one block per batch b). Everything staged to LDS up front.
__global__ __launch_bounds__(256, 1) void post_kernel(
    const float* __restrict__ y, const float* __restrict__ Mws,
    const float* __restrict__ ln_g, const float* __restrict__ ln_b,
    const float* __restrict__ fc_w, const float* __restrict__ fc_b,
    float* __restrict__ out)
{
  __shared__ float ysh[128*65];  // [n][h] stride 65
  __shared__ float Mre[65*65];   // [k][h] stride 65
  __shared__ float Mim[65*65];
  __shared__ float twc[128], tws[128];
  __shared__ float Sre[64], Sim[64];
  __shared__ float gr[65], gi[65];
  __shared__ float Gre[64], Gim[64];
  __shared__ float att[128];
  __shared__ float PQ[65*2], AA[65*2];
  __shared__ float outv[64];

  const int b   = blockIdx.x;
  const int tid = threadIdx.x;

  if (tid < 128){
    float ang = (float)((double)tid * 0.04908738521234052);
    twc[tid] = cosf(ang);
    tws[tid] = sinf(ang);
  }
  for (int i = tid; i < 128*16; i += 256){
    int nn = i >> 4, h4 = (i & 15)*4;
    float4 v = *(const float4*)&y[(b*N_NODES + nn)*H_SZ + h4];
    ysh[nn*65 + h4+0] = v.x; ysh[nn*65 + h4+1] = v.y;
    ysh[nn*65 + h4+2] = v.z; ysh[nn*65 + h4+3] = v.w;
  }
  for (int i = tid; i < 65*16; i += 256){
    int k = i >> 4, h4 = (i & 15)*4;
    float4 vr = *(const float4*)&Mws[((b*2+0)*65 + k)*H_SZ + h4];
    float4 vi = *(const float4*)&Mws[((b*2+1)*65 + k)*H_SZ + h4];
    Mre[k*65 + h4+0] = vr.x; Mre[k*65 + h4+1] = vr.y;
    Mre[k*65 + h4+2] = vr.z; Mre[k*65 + h4+3] = vr.w;
    Mim[k*65 + h4+0] = vi.x; Mim[k*65 + h4+1] = vi.y;
    Mim[k*65 + h4+2] = vi.z; Mim[k*65 + h4+3] = vi.w;
  }
  __syncthreads();

  if (tid < 64){
    float sr=0, si=0;
    for (int k = 0; k < 65; ++k){ sr += Mre[k*65+tid]; si += Mim[k*65+tid]; }
    Sre[tid]=sr; Sim[tid]=si;
  }
  __syncthreads();

  if (tid < 65){
    float a=0, bb=0;
    for (int h = 0; h < 64; ++h){
      float mr = Mre[tid*65+h], mi = Mim[tid*65+h];
      a  += mr*Sre[h] - mi*Sim[h];
      bb += mr*Sim[h] + mi*Sre[h];
    }
    a  *= (1.0f/4160.0f);  bb *= (1.0f/4160.0f);
    a = fmaxf(a, 0.0f);    bb = fmaxf(bb, 0.0f);
    float t  = __expf(-a);
    float cb = cosf(bb), sb = sinf(bb);
    float dre = 1.0f + t*cb;
    float dim = t*sb;
    float nrm = rcp_fast(dre*dre + dim*dim);
    gr[tid] = dre*nrm;
    gi[tid] = dim*nrm;
  }
  __syncthreads();

  if (tid < 64){
    float grh=0, gih=0;
    for (int k = 0; k < 65; ++k){
      float mr = Mre[k*65+tid], mi = Mim[k*65+tid];
      float gk = gr[k], hk = gi[k];
      grh += gk*mr - hk*mi;
      gih += gk*mi + hk*mr;
    }
    Gre[tid]=grh; Gim[tid]=gih;
  }
  __syncthreads();

  if (tid < 65){
    float p=0, qq=0;
    for (int h = 0; h < 64; ++h){
      float gimh = Gim[h];
      p  += gimh * Mim[tid*65+h];
      qq += gimh * Mre[tid*65+h];
    }
    const float s2 = 2.0f*0.08838834764831845f;
    PQ[tid*2]   = p*s2;
    PQ[tid*2+1] = qq*s2;
  }
  __syncthreads();

  if (tid < 128){
    float u=0;
    for (int h = 0; h < 64; ++h) u += Gre[h]*ysh[tid*65+h];
    float v=0;
    for (int k = 1; k < 64; ++k){
      int j = (k*tid) & 127;
      v += PQ[k*2]*twc[j] + PQ[k*2+1]*tws[j];
    }
    float mean = (u - v)*(1.0f/64.0f);
    att[tid] = sigm(fmaxf(mean, 0.0f));
  }
  __syncthreads();

  if (tid < 65){
    float ac=0, as=0;
    for (int nn = 0; nn < 128; ++nn){
      int j = (tid*nn) & 127;
      float a2 = att[nn];
      ac = fmaf(a2, twc[j], ac);
      as = fmaf(a2, tws[j], as);
    }
    const float s2 = 2.0f*0.08838834764831845f;
    AA[tid*2]   = ac*s2;
    AA[tid*2+1] = as*s2;
  }
  __syncthreads();

  if (tid < 64){
    float wyh=0;
    for (int nn = 0; nn < 128; ++nn) wyh += att[nn]*ysh[nn*65+tid];
    float wHh=0;
    for (int k = 1; k < 64; ++k)
      wHh += Mim[k*65+tid]*AA[k*2] + Mre[k*65+tid]*AA[k*2+1];
    outv[tid] = Gre[tid]*wyh - Gim[tid]*wHh;
  }
  __syncthreads();

  if (tid < 64){
    float o = outv[tid];
    float s = o;
    for (int off = 32; off; off >>= 1) s += __shfl_xor(s, off, 64);
    float mu = s*(1.0f/64.0f);
    float d  = o - mu;
    float vv = d*d;
    for (int off = 32; off; off >>= 1) vv += __shfl_xor(vv, off, 64);
    float var = vv*(1.0f/64.0f);
    float zo = (d / sqrtf(var + 1e-5f))*ln_g[tid] + ln_b[tid];
    float z  = zo * fc_w[tid];
    for (int off = 32; off; off >>= 1) z += __shfl_xor(z, off, 64);
    if (tid == 0) out[b] = 1.0f/(1.0f + __expf(-(z + fc_b[0])));
  }
}

extern "C" void kernel_launch(void* const* d_in, const int* in_sizes, int n_in,
                              void* d_out, int out_size, void* d_ws, size_t ws_size,
                              hipStream_t stream) {
  (void)in_sizes; (void)n_in; (void)out_size; (void)ws_size;
  const float* x    = (const float*)d_in[0];
  const float* w    = (const float*)d_in[1];
  const float* bia  = (const float*)d_in[2];
  const float* ln_g = (const float*)d_in[3];
  const float* ln_b = (const float*)d_in[4];
  const float* fc_w = (const float*)d_in[5];
  const float* fc_b = (const float*)d_in[6];
  float* out = (float*)d_out;

  float* y = (float*)d_ws;                  // [64][128][64] fp32  (2 MB)
  float* M = y + (size_t)B_SZ*N_NODES*H_SZ; // [64][2][65][64] fp32 (~2.1 MB)

  lstm_kernel<<<dim3(512), dim3(256), 0, stream>>>(x, w, bia, y);
  dft_kernel <<<dim3(256), dim3(256), 0, stream>>>(y, M);
  post_kernel<<<dim3(64),  dim3(256), 0, stream>>>(y, M, ln_g, ln_b, fc_w, fc_b, out);
}